// Round 1
// baseline (431.529 us; speedup 1.0000x reference)
//
#include <hip/hip_runtime.h>
#include <math.h>

// Problem constants
#define BB 4
#define SS 1024
#define DD 1024
#define HH 16
#define HDIM 64
#define FF 4096
#define MM 4096   // B*S

typedef short bf16x8 __attribute__((ext_vector_type(8)));
typedef short bf16x4 __attribute__((ext_vector_type(4)));
typedef float f32x4  __attribute__((ext_vector_type(4)));

static __device__ __forceinline__ short f2bf(float f){
  unsigned u = __float_as_uint(f);
  u += 0x7FFFu + ((u >> 16) & 1u);   // RNE
  return (short)(u >> 16);
}

// ---------------- weight f32 -> bf16 transposed ----------------
// src [R][C] f32  ->  dst [C][R] bf16
__global__ __launch_bounds__(256) void trans_bf16_kernel(const float* __restrict__ src,
                                                         short* __restrict__ dst,
                                                         int R, int C){
  __shared__ float t[32][33];
  int c0 = blockIdx.x * 32, r0 = blockIdx.y * 32;
  int tx = threadIdx.x, ty = threadIdx.y;  // (32,8)
#pragma unroll
  for (int i = 0; i < 32; i += 8)
    t[ty + i][tx] = src[(size_t)(r0 + ty + i) * C + (c0 + tx)];
  __syncthreads();
#pragma unroll
  for (int i = 0; i < 32; i += 8)
    dst[(size_t)(c0 + ty + i) * R + (r0 + tx)] = f2bf(t[tx][ty + i]);
}

// ---------------- embedding + sinusoidal PE ----------------
__global__ __launch_bounds__(256) void embed_kernel(const int* __restrict__ inputs,
                                                    const float* __restrict__ wte,
                                                    float* __restrict__ xf,
                                                    short* __restrict__ xb){
  int idx4 = blockIdx.x * 256 + threadIdx.x;   // 1M quads
  int row = idx4 >> 8;            // 0..4095  (b*S+s)
  int d   = (idx4 & 255) * 4;
  int s   = row & (SS - 1);
  int tok = inputs[row];
  float4 w = *(const float4*)&wte[(size_t)tok * DD + d];
  const float cdiv = -9.210340371976184f / 512.0f;   // -ln(10000)/(D/2)
  int i0 = d >> 1;
  float ang0 = (float)s * expf((float)i0 * cdiv);
  float ang1 = (float)s * expf((float)(i0 + 1) * cdiv);
  float x0 = w.x + sinf(ang0);
  float x1 = w.y + cosf(ang0);
  float x2 = w.z + sinf(ang1);
  float x3 = w.w + cosf(ang1);
  *(float4*)&xf[(size_t)row * DD + d] = make_float4(x0, x1, x2, x3);
  bf16x4 sb; sb[0]=f2bf(x0); sb[1]=f2bf(x1); sb[2]=f2bf(x2); sb[3]=f2bf(x3);
  *(bf16x4*)&xb[(size_t)row * DD + d] = sb;
}

// ---------------- bf16 MFMA GEMM:  C[M][N] = A[M][K] * Bt[N][K]^T + bias ----------------
// 128x128 tile, BK=32, 256 threads (4 waves, 2x2), each wave 64x64 (4x4 16x16 frags)
template<bool GELU, bool WF32, bool WBF16>
__global__ __launch_bounds__(256) void gemm_kernel(const short* __restrict__ A,
                                                   const short* __restrict__ Bt,
                                                   const float* __restrict__ bias,
                                                   float* __restrict__ Cf,
                                                   short* __restrict__ Cb,
                                                   int M, int N, int K){
  __shared__ __align__(16) short a_lds[128 * 40];
  __shared__ __align__(16) short b_lds[128 * 40];
  int tid = threadIdx.x;
  int m0 = blockIdx.y * 128, n0 = blockIdx.x * 128;
  int w = tid >> 6, lane = tid & 63, lr = lane & 15, lg = lane >> 4;
  int wm = (w & 1) * 64, wn = (w >> 1) * 64;
  f32x4 acc[4][4] = {};

  for (int k0 = 0; k0 < K; k0 += 32){
#pragma unroll
    for (int i = 0; i < 2; i++){
      int c = tid + i * 256;          // 512 chunks of 8 bf16
      int row = c >> 2, col = (c & 3) * 8;
      *(int4*)&a_lds[row * 40 + col] = *(const int4*)&A[(size_t)(m0 + row) * K + k0 + col];
      *(int4*)&b_lds[row * 40 + col] = *(const int4*)&Bt[(size_t)(n0 + row) * K + k0 + col];
    }
    __syncthreads();
    bf16x8 af[4], bfr[4];
#pragma unroll
    for (int mi = 0; mi < 4; mi++)
      af[mi] = *(const bf16x8*)&a_lds[(wm + mi * 16 + lr) * 40 + lg * 8];
#pragma unroll
    for (int ni = 0; ni < 4; ni++)
      bfr[ni] = *(const bf16x8*)&b_lds[(wn + ni * 16 + lr) * 40 + lg * 8];
#pragma unroll
    for (int mi = 0; mi < 4; mi++)
#pragma unroll
      for (int ni = 0; ni < 4; ni++)
        acc[mi][ni] = __builtin_amdgcn_mfma_f32_16x16x32_bf16(af[mi], bfr[ni], acc[mi][ni], 0, 0, 0);
    __syncthreads();
  }

#pragma unroll
  for (int mi = 0; mi < 4; mi++){
#pragma unroll
    for (int ni = 0; ni < 4; ni++){
      int ng = n0 + wn + ni * 16 + lr;
      float bv = bias[ng];
#pragma unroll
      for (int r = 0; r < 4; r++){
        int mg = m0 + wm + mi * 16 + 4 * lg + r;
        float v = acc[mi][ni][r] + bv;
        if (GELU) v = 0.5f * v * (1.0f + erff(v * 0.70710678118654752f));
        if (WF32)  Cf[(size_t)mg * N + ng] = v;
        if (WBF16) Cb[(size_t)mg * N + ng] = f2bf(v);
      }
    }
  }
}

// ---------------- causal flash attention ----------------
// 1 wave per (b, h, 16-row q-tile); KVBLK=32
__global__ __launch_bounds__(64) void attn_kernel(const short* __restrict__ qb,
                                                  const short* __restrict__ kb,
                                                  const short* __restrict__ vb,
                                                  short* __restrict__ ctxb){
  __shared__ __align__(16) short v_lds[32 * 72];
  __shared__ __align__(16) short p_lds[16 * 40];
  int qt = blockIdx.x, h = blockIdx.y, b = blockIdx.z;
  int tid = threadIdx.x, lr = tid & 15, lg = tid >> 4;
  int qbase = qt * 16;

  const short* qp = qb + ((size_t)(b * SS + qbase) * DD + h * HDIM);
  bf16x8 qf0 = *(const bf16x8*)&qp[lr * DD + lg * 8];
  bf16x8 qf1 = *(const bf16x8*)&qp[lr * DD + lg * 8 + 32];

  float m[4], l[4];
  f32x4 acc[4] = {};
#pragma unroll
  for (int r = 0; r < 4; r++){ m[r] = -1e30f; l[r] = 0.0f; }

  int ntiles = qt / 2 + 1;
  for (int kt = 0; kt < ntiles; kt++){
    int kbase = kt * 32;
    const short* kp = kb + ((size_t)(b * SS + kbase) * DD + h * HDIM);
    const short* vp = vb + ((size_t)(b * SS + kbase) * DD + h * HDIM);

    bf16x8 kf0a = *(const bf16x8*)&kp[lr * DD + lg * 8];
    bf16x8 kf0b = *(const bf16x8*)&kp[lr * DD + lg * 8 + 32];
    bf16x8 kf1a = *(const bf16x8*)&kp[(16 + lr) * DD + lg * 8];
    bf16x8 kf1b = *(const bf16x8*)&kp[(16 + lr) * DD + lg * 8 + 32];

    f32x4 s0 = {}, s1 = {};
    s0 = __builtin_amdgcn_mfma_f32_16x16x32_bf16(qf0, kf0a, s0, 0, 0, 0);
    s0 = __builtin_amdgcn_mfma_f32_16x16x32_bf16(qf1, kf0b, s0, 0, 0, 0);
    s1 = __builtin_amdgcn_mfma_f32_16x16x32_bf16(qf0, kf1a, s1, 0, 0, 0);
    s1 = __builtin_amdgcn_mfma_f32_16x16x32_bf16(qf1, kf1b, s1, 0, 0, 0);

#pragma unroll
    for (int r = 0; r < 4; r++){ s0[r] *= 0.125f; s1[r] *= 0.125f; }

    if (kt == ntiles - 1){
#pragma unroll
      for (int r = 0; r < 4; r++){
        int qrow = qbase + 4 * lg + r;
        if (kbase + lr      > qrow) s0[r] = -1e30f;
        if (kbase + 16 + lr > qrow) s1[r] = -1e30f;
      }
    }

    float pm[4];
#pragma unroll
    for (int r = 0; r < 4; r++) pm[r] = fmaxf(s0[r], s1[r]);
#pragma unroll
    for (int off = 1; off < 16; off <<= 1)
#pragma unroll
      for (int r = 0; r < 4; r++) pm[r] = fmaxf(pm[r], __shfl_xor(pm[r], off));

    float sc[4], p0[4], p1[4], rs[4];
#pragma unroll
    for (int r = 0; r < 4; r++){
      float mn = fmaxf(m[r], pm[r]);
      sc[r] = expf(m[r] - mn);
      m[r] = mn;
      p0[r] = expf(s0[r] - mn);
      p1[r] = expf(s1[r] - mn);
      rs[r] = p0[r] + p1[r];
    }
#pragma unroll
    for (int off = 1; off < 16; off <<= 1)
#pragma unroll
      for (int r = 0; r < 4; r++) rs[r] += __shfl_xor(rs[r], off);
#pragma unroll
    for (int r = 0; r < 4; r++) l[r] = l[r] * sc[r] + rs[r];
#pragma unroll
    for (int nb = 0; nb < 4; nb++)
#pragma unroll
      for (int r = 0; r < 4; r++) acc[nb][r] *= sc[r];

    __syncthreads();
#pragma unroll
    for (int r = 0; r < 4; r++){
      int qr = 4 * lg + r;
      p_lds[qr * 40 + lr]      = f2bf(p0[r]);
      p_lds[qr * 40 + 16 + lr] = f2bf(p1[r]);
    }
    // stage V tile 32x64
#pragma unroll
    for (int i = 0; i < 4; i++){
      int c = tid + i * 64;
      int row = c >> 3, col = (c & 7) * 8;
      *(int4*)&v_lds[row * 72 + col] = *(const int4*)&vp[(size_t)row * DD + col];
    }
    __syncthreads();

    bf16x8 pf = *(const bf16x8*)&p_lds[lr * 40 + lg * 8];
#pragma unroll
    for (int nb = 0; nb < 4; nb++){
      bf16x8 vf;
#pragma unroll
      for (int j = 0; j < 8; j++) vf[j] = v_lds[(8 * lg + j) * 72 + 16 * nb + lr];
      acc[nb] = __builtin_amdgcn_mfma_f32_16x16x32_bf16(pf, vf, acc[nb], 0, 0, 0);
    }
  }

#pragma unroll
  for (int r = 0; r < 4; r++){
    float inv = 1.0f / l[r];
    int row = qbase + 4 * lg + r;
#pragma unroll
    for (int nb = 0; nb < 4; nb++){
      int col = h * HDIM + 16 * nb + lr;
      ctxb[(size_t)(b * SS + row) * DD + col] = f2bf(acc[nb][r] * inv);
    }
  }
}

// ---------------- LayerNorm(a+b) ----------------
template<bool WBF16>
__global__ __launch_bounds__(256) void ln_kernel(const float* __restrict__ a,
                                                 const float* __restrict__ bsrc,
                                                 const float* __restrict__ g,
                                                 const float* __restrict__ be,
                                                 float* __restrict__ of,
                                                 short* __restrict__ ob){
  int row = blockIdx.x, tid = threadIdx.x;
  float4 av = *(const float4*)&a[(size_t)row * DD + tid * 4];
  float4 bv = *(const float4*)&bsrc[(size_t)row * DD + tid * 4];
  float x0 = av.x + bv.x, x1 = av.y + bv.y, x2 = av.z + bv.z, x3 = av.w + bv.w;
  float s = x0 + x1 + x2 + x3;
  float q = x0 * x0 + x1 * x1 + x2 * x2 + x3 * x3;
#pragma unroll
  for (int off = 32; off; off >>= 1){ s += __shfl_xor(s, off); q += __shfl_xor(q, off); }
  __shared__ float red[8];
  if ((tid & 63) == 0){ red[tid >> 6] = s; red[4 + (tid >> 6)] = q; }
  __syncthreads();
  s = red[0] + red[1] + red[2] + red[3];
  q = red[4] + red[5] + red[6] + red[7];
  float mean = s * (1.0f / DD);
  float var  = q * (1.0f / DD) - mean * mean;
  float rstd = rsqrtf(var + 1e-5f);
  float4 gv  = *(const float4*)&g[tid * 4];
  float4 bev = *(const float4*)&be[tid * 4];
  float y0 = (x0 - mean) * rstd * gv.x + bev.x;
  float y1 = (x1 - mean) * rstd * gv.y + bev.y;
  float y2 = (x2 - mean) * rstd * gv.z + bev.z;
  float y3 = (x3 - mean) * rstd * gv.w + bev.w;
  *(float4*)&of[(size_t)row * DD + tid * 4] = make_float4(y0, y1, y2, y3);
  if (WBF16){
    bf16x4 sb; sb[0]=f2bf(y0); sb[1]=f2bf(y1); sb[2]=f2bf(y2); sb[3]=f2bf(y3);
    *(bf16x4*)&ob[(size_t)row * DD + tid * 4] = sb;
  }
}

// ---------------- cross-entropy ----------------
__global__ __launch_bounds__(256) void loss_row_kernel(const float* __restrict__ logits,
                                                       const int* __restrict__ tgt,
                                                       float* __restrict__ outp){
  int row = blockIdx.x, tid = threadIdx.x;
  float4 v = *(const float4*)&logits[(size_t)row * DD + tid * 4];
  float mx = fmaxf(fmaxf(v.x, v.y), fmaxf(v.z, v.w));
#pragma unroll
  for (int off = 32; off; off >>= 1) mx = fmaxf(mx, __shfl_xor(mx, off));
  __shared__ float red[8];
  if ((tid & 63) == 0) red[tid >> 6] = mx;
  __syncthreads();
  mx = fmaxf(fmaxf(red[0], red[1]), fmaxf(red[2], red[3]));
  float se = expf(v.x - mx) + expf(v.y - mx) + expf(v.z - mx) + expf(v.w - mx);
#pragma unroll
  for (int off = 32; off; off >>= 1) se += __shfl_xor(se, off);
  __syncthreads();
  if ((tid & 63) == 0) red[4 + (tid >> 6)] = se;
  __syncthreads();
  if (tid == 0){
    float tot = red[4] + red[5] + red[6] + red[7];
    outp[row] = mx + logf(tot) - logits[(size_t)row * DD + tgt[row]];
  }
}

__global__ __launch_bounds__(256) void loss_reduce_kernel(const float* __restrict__ pr,
                                                          float* __restrict__ outp){
  int tid = threadIdx.x;
  float s = 0.0f;
  for (int i = tid; i < MM; i += 256) s += pr[i];
#pragma unroll
  for (int off = 32; off; off >>= 1) s += __shfl_xor(s, off);
  __shared__ float red[4];
  if ((tid & 63) == 0) red[tid >> 6] = s;
  __syncthreads();
  if (tid == 0) outp[0] = (red[0] + red[1] + red[2] + red[3]) * (1.0f / MM);
}

// ---------------- launch ----------------
extern "C" void kernel_launch(void* const* d_in, const int* in_sizes, int n_in,
                              void* d_out, int out_size, void* d_ws, size_t ws_size,
                              hipStream_t stream){
  const int*   inputs  = (const int*)  d_in[0];
  const int*   targets = (const int*)  d_in[1];
  const float* wte     = (const float*)d_in[2];
  const float* wq      = (const float*)d_in[3];
  const float* bq      = (const float*)d_in[4];
  const float* wk      = (const float*)d_in[5];
  const float* bk      = (const float*)d_in[6];
  const float* wv      = (const float*)d_in[7];
  const float* bvv     = (const float*)d_in[8];
  const float* wo      = (const float*)d_in[9];
  const float* bo      = (const float*)d_in[10];
  const float* w1      = (const float*)d_in[11];
  const float* b1      = (const float*)d_in[12];
  const float* w2      = (const float*)d_in[13];
  const float* b2      = (const float*)d_in[14];
  const float* ln1g    = (const float*)d_in[15];
  const float* ln1b    = (const float*)d_in[16];
  const float* ln2g    = (const float*)d_in[17];
  const float* ln2b    = (const float*)d_in[18];
  float* out = (float*)d_out;

  char* ws = (char*)d_ws;
  const size_t MB = 1024 * 1024;
  short* wqt  = (short*)(ws + 0 * MB);     // 2MB each
  short* wkt  = (short*)(ws + 2 * MB);
  short* wvt  = (short*)(ws + 4 * MB);
  short* wot  = (short*)(ws + 6 * MB);
  short* w1t  = (short*)(ws + 8 * MB);     // 8MB
  short* w2t  = (short*)(ws + 16 * MB);    // 8MB
  float* xf   = (float*)(ws + 24 * MB);    // 16MB
  short* xb   = (short*)(ws + 40 * MB);    // 8MB
  short* qbuf = (short*)(ws + 48 * MB);    // 8MB
  short* kbuf = (short*)(ws + 56 * MB);    // 8MB
  short* vbuf = (short*)(ws + 64 * MB);    // 8MB
  short* ctxb = (short*)(ws + 72 * MB);    // 8MB
  float* atto = (float*)(ws + 80 * MB);    // 16MB
  float* adnf = (float*)(ws + 96 * MB);    // 16MB
  short* adnb = (short*)(ws + 112 * MB);   // 8MB
  short* h1b  = (short*)(ws + 48 * MB);    // 32MB, reuses q/k/v/ctx (dead after proj)
  float* hf   = (float*)(ws + 120 * MB);   // 16MB
  float* lrow = (float*)(ws + 136 * MB);   // 16KB

  dim3 tb(32, 8);
  trans_bf16_kernel<<<dim3(32, 32),  tb, 0, stream>>>(wq, wqt, DD, DD);
  trans_bf16_kernel<<<dim3(32, 32),  tb, 0, stream>>>(wk, wkt, DD, DD);
  trans_bf16_kernel<<<dim3(32, 32),  tb, 0, stream>>>(wv, wvt, DD, DD);
  trans_bf16_kernel<<<dim3(32, 32),  tb, 0, stream>>>(wo, wot, DD, DD);
  trans_bf16_kernel<<<dim3(128, 32), tb, 0, stream>>>(w1, w1t, DD, FF);
  trans_bf16_kernel<<<dim3(32, 128), tb, 0, stream>>>(w2, w2t, FF, DD);

  embed_kernel<<<4096, 256, 0, stream>>>(inputs, wte, xf, xb);

  gemm_kernel<false, false, true><<<dim3(8, 32), 256, 0, stream>>>(xb, wqt, bq, nullptr, qbuf, MM, DD, DD);
  gemm_kernel<false, false, true><<<dim3(8, 32), 256, 0, stream>>>(xb, wkt, bk, nullptr, kbuf, MM, DD, DD);
  gemm_kernel<false, false, true><<<dim3(8, 32), 256, 0, stream>>>(xb, wvt, bvv, nullptr, vbuf, MM, DD, DD);

  attn_kernel<<<dim3(64, 16, 4), 64, 0, stream>>>(qbuf, kbuf, vbuf, ctxb);

  gemm_kernel<false, true, false><<<dim3(8, 32), 256, 0, stream>>>(ctxb, wot, bo, atto, nullptr, MM, DD, DD);

  ln_kernel<true><<<4096, 256, 0, stream>>>(xf, atto, ln1g, ln1b, adnf, adnb);

  gemm_kernel<true, false, true><<<dim3(32, 32), 256, 0, stream>>>(adnb, w1t, b1, nullptr, h1b, MM, FF, DD);
  gemm_kernel<false, true, false><<<dim3(8, 32), 256, 0, stream>>>(h1b, w2t, b2, hf, nullptr, MM, DD, FF);

  ln_kernel<false><<<4096, 256, 0, stream>>>(hf, adnf, ln2g, ln2b, out, nullptr);

  loss_row_kernel<<<4096, 256, 0, stream>>>(out, targets, lrow);
  loss_reduce_kernel<<<1, 256, 0, stream>>>(lrow, out + (size_t)MM * DD);
}

// Round 3
// 411.077 us; speedup vs baseline: 1.0498x; 1.0498x over previous
//
#include <hip/hip_runtime.h>
#include <math.h>

// Problem constants
#define BB 4
#define SS 1024
#define DD 1024
#define HH 16
#define HDIM 64
#define FF 4096
#define MM 4096   // B*S

typedef short bf16x8 __attribute__((ext_vector_type(8)));
typedef short bf16x4 __attribute__((ext_vector_type(4)));
typedef float f32x4  __attribute__((ext_vector_type(4)));

static __device__ __forceinline__ short f2bf(float f){
  unsigned u = __float_as_uint(f);
  u += 0x7FFFu + ((u >> 16) & 1u);   // RNE
  return (short)(u >> 16);
}

// async global->LDS, 16B per lane, LDS dest = base + lane*16 (wave-uniform base)
static __device__ __forceinline__ void gl_lds16(const short* g, short* l){
  __builtin_amdgcn_global_load_lds((const __attribute__((address_space(1))) unsigned int*)g,
                                   (__attribute__((address_space(3))) unsigned int*)l,
                                   16, 0, 0);
}

// ---------------- weight f32 -> bf16 transposed ----------------
__global__ __launch_bounds__(256) void trans_bf16_kernel(const float* __restrict__ src,
                                                         short* __restrict__ dst,
                                                         int R, int C){
  __shared__ float t[32][33];
  int c0 = blockIdx.x * 32, r0 = blockIdx.y * 32;
  int tx = threadIdx.x, ty = threadIdx.y;  // (32,8)
#pragma unroll
  for (int i = 0; i < 32; i += 8)
    t[ty + i][tx] = src[(size_t)(r0 + ty + i) * C + (c0 + tx)];
  __syncthreads();
#pragma unroll
  for (int i = 0; i < 32; i += 8)
    dst[(size_t)(c0 + ty + i) * R + (r0 + tx)] = f2bf(t[tx][ty + i]);
}

__global__ __launch_bounds__(256) void concat_bias_kernel(const float* __restrict__ a,
                                                          const float* __restrict__ b,
                                                          const float* __restrict__ c,
                                                          float* __restrict__ dst){
  int t = blockIdx.x * 256 + threadIdx.x;   // 3072
  float v = (t < 1024) ? a[t] : (t < 2048 ? b[t - 1024] : c[t - 2048]);
  dst[t] = v;
}

// ---------------- embedding + sinusoidal PE ----------------
__global__ __launch_bounds__(256) void embed_kernel(const int* __restrict__ inputs,
                                                    const float* __restrict__ wte,
                                                    float* __restrict__ xf,
                                                    short* __restrict__ xb){
  int idx4 = blockIdx.x * 256 + threadIdx.x;
  int row = idx4 >> 8;
  int d   = (idx4 & 255) * 4;
  int s   = row & (SS - 1);
  int tok = inputs[row];
  float4 w = *(const float4*)&wte[(size_t)tok * DD + d];
  const float cdiv = -9.210340371976184f / 512.0f;
  int i0 = d >> 1;
  float ang0 = (float)s * expf((float)i0 * cdiv);
  float ang1 = (float)s * expf((float)(i0 + 1) * cdiv);
  float x0 = w.x + sinf(ang0);
  float x1 = w.y + cosf(ang0);
  float x2 = w.z + sinf(ang1);
  float x3 = w.w + cosf(ang1);
  *(float4*)&xf[(size_t)row * DD + d] = make_float4(x0, x1, x2, x3);
  bf16x4 sb; sb[0]=f2bf(x0); sb[1]=f2bf(x1); sb[2]=f2bf(x2); sb[3]=f2bf(x3);
  *(bf16x4*)&xb[(size_t)row * DD + d] = sb;
}

// ---------------- 128x128 MFMA GEMM (m97 structure, global_load_lds) ----------------
// MODE 0: bf16 row-major (opt GELU); 1: f32 row-major; 2: QKV split (q,k row-major; v transposed)
template<int MODE, bool GELU>
__global__ __launch_bounds__(256) void gemm128_kernel(const short* __restrict__ A,
    const short* __restrict__ Bt, const float* __restrict__ bias,
    float* __restrict__ Cf, short* __restrict__ Cb,
    short* __restrict__ qo, short* __restrict__ ko, short* __restrict__ vto,
    int M, int N, int K){
  __shared__ __align__(16) short a_lds[128 * 32];
  __shared__ __align__(16) short b_lds[128 * 32];
  int tid = threadIdx.x;
  int m0 = blockIdx.y * 128, n0 = blockIdx.x * 128;
  int w = tid >> 6, lane = tid & 63, lr = lane & 15, lg = lane >> 4;
  int wm = (w & 1) * 64, wn = (w >> 1) * 64;
  int srow = lane >> 2, scol = (lane & 3) * 8;
  f32x4 acc[4][4] = {};

  for (int k0 = 0; k0 < K; k0 += 32){
#pragma unroll
    for (int i = 0; i < 2; i++){
      int rb = (w + 4 * i) * 16;
      gl_lds16(&A [(size_t)(m0 + rb + srow) * K + k0 + scol], &a_lds[rb * 32]);
      gl_lds16(&Bt[(size_t)(n0 + rb + srow) * K + k0 + scol], &b_lds[rb * 32]);
    }
    asm volatile("s_waitcnt vmcnt(0)" ::: "memory");
    __syncthreads();
    bf16x8 af[4], bfr[4];
#pragma unroll
    for (int mi = 0; mi < 4; mi++)
      af[mi] = *(const bf16x8*)&a_lds[(wm + mi * 16 + lr) * 32 + lg * 8];
#pragma unroll
    for (int ni = 0; ni < 4; ni++)
      bfr[ni] = *(const bf16x8*)&b_lds[(wn + ni * 16 + lr) * 32 + lg * 8];
#pragma unroll
    for (int mi = 0; mi < 4; mi++)
#pragma unroll
      for (int ni = 0; ni < 4; ni++)
        acc[mi][ni] = __builtin_amdgcn_mfma_f32_16x16x32_bf16(af[mi], bfr[ni], acc[mi][ni], 0, 0, 0);
    __syncthreads();
  }

#pragma unroll
  for (int mi = 0; mi < 4; mi++){
#pragma unroll
    for (int ni = 0; ni < 4; ni++){
      int ng = n0 + wn + ni * 16 + lr;
      float bv = bias[ng];
      int mg0 = m0 + wm + mi * 16 + 4 * lg;   // 4 consecutive rows
      if (MODE == 2){
        int sel = n0 >> 10;   // uniform per block (128 | 1024)
        if (sel == 2){
          int d = ng & 1023; int hh = d >> 6, nn = d & 63;
          int bI = mg0 >> 10, sI = mg0 & 1023;
          bf16x4 pk;
#pragma unroll
          for (int r = 0; r < 4; r++) pk[r] = f2bf(acc[mi][ni][r] + bv);
          *(bf16x4*)&vto[(((size_t)(bI * HH + hh)) * HDIM + nn) * SS + sI] = pk;
        } else {
          short* dst = (sel == 0) ? qo : ko;
#pragma unroll
          for (int r = 0; r < 4; r++)
            dst[(size_t)(mg0 + r) * DD + (ng & 1023)] = f2bf(acc[mi][ni][r] + bv);
        }
      } else {
#pragma unroll
        for (int r = 0; r < 4; r++){
          float v = acc[mi][ni][r] + bv;
          if (GELU) v = 0.5f * v * (1.0f + erff(v * 0.70710678118654752f));
          if (MODE == 0) Cb[(size_t)(mg0 + r) * N + ng] = f2bf(v);
          else           Cf[(size_t)(mg0 + r) * N + ng] = v;
        }
      }
    }
  }
}

// ---------------- 128x64 MFMA GEMM (2 blocks/CU for N=1024 shapes), f32 out ----------------
__global__ __launch_bounds__(256) void gemm64_kernel(const short* __restrict__ A,
    const short* __restrict__ Bt, const float* __restrict__ bias,
    float* __restrict__ Cf, int M, int N, int K){
  __shared__ __align__(16) short a_lds[128 * 32];
  __shared__ __align__(16) short b_lds[64 * 32];
  int tid = threadIdx.x;
  int m0 = blockIdx.y * 128, n0 = blockIdx.x * 64;
  int w = tid >> 6, lane = tid & 63, lr = lane & 15, lg = lane >> 4;
  int wm = w * 32;
  int srow = lane >> 2, scol = (lane & 3) * 8;
  f32x4 acc[2][4] = {};

  for (int k0 = 0; k0 < K; k0 += 32){
#pragma unroll
    for (int i = 0; i < 2; i++){
      int rb = (w + 4 * i) * 16;
      gl_lds16(&A[(size_t)(m0 + rb + srow) * K + k0 + scol], &a_lds[rb * 32]);
    }
    { int rb = w * 16;
      gl_lds16(&Bt[(size_t)(n0 + rb + srow) * K + k0 + scol], &b_lds[rb * 32]); }
    asm volatile("s_waitcnt vmcnt(0)" ::: "memory");
    __syncthreads();
    bf16x8 af[2], bfr[4];
#pragma unroll
    for (int mi = 0; mi < 2; mi++)
      af[mi] = *(const bf16x8*)&a_lds[(wm + mi * 16 + lr) * 32 + lg * 8];
#pragma unroll
    for (int ni = 0; ni < 4; ni++)
      bfr[ni] = *(const bf16x8*)&b_lds[(ni * 16 + lr) * 32 + lg * 8];
#pragma unroll
    for (int mi = 0; mi < 2; mi++)
#pragma unroll
      for (int ni = 0; ni < 4; ni++)
        acc[mi][ni] = __builtin_amdgcn_mfma_f32_16x16x32_bf16(af[mi], bfr[ni], acc[mi][ni], 0, 0, 0);
    __syncthreads();
  }

#pragma unroll
  for (int mi = 0; mi < 2; mi++)
#pragma unroll
    for (int ni = 0; ni < 4; ni++){
      int ng = n0 + ni * 16 + lr;
      float bv = bias[ng];
      int mg0 = m0 + wm + mi * 16 + 4 * lg;
#pragma unroll
      for (int r = 0; r < 4; r++)
        Cf[(size_t)(mg0 + r) * N + ng] = acc[mi][ni][r] + bv;
    }
}

// ---------------- causal flash attention v2 ----------------
// 4 waves/block, wave w: 16 q-rows; KVBLK=64; K from global (L2), V from VT global (L2)
__global__ __launch_bounds__(256) void attn_kernel(const short* __restrict__ qb,
                                                   const short* __restrict__ kb,
                                                   const short* __restrict__ vtb,
                                                   short* __restrict__ ctxb){
  __shared__ __align__(16) short p_lds[4][16 * 72];
  int qt = blockIdx.x, h = blockIdx.y, b = blockIdx.z;
  int tid = threadIdx.x, w = tid >> 6, lane = tid & 63, lr = lane & 15, lg = lane >> 4;
  int qbase = qt * 64 + w * 16;
  short* pw = &p_lds[w][0];

  const short* qp = qb + ((size_t)(b * SS + qbase) * DD + h * HDIM);
  bf16x8 qf0 = *(const bf16x8*)&qp[lr * DD + lg * 8];
  bf16x8 qf1 = *(const bf16x8*)&qp[lr * DD + 32 + lg * 8];
  const short* kp0 = kb + (size_t)b * SS * DD + h * HDIM;
  const short* vt0 = vtb + (size_t)(b * HH + h) * HDIM * SS;   // [64][1024]

  float m[4], l[4];
  f32x4 acc[4] = {};
#pragma unroll
  for (int r = 0; r < 4; r++){ m[r] = -1e30f; l[r] = 0.0f; }

  for (int kt = 0; kt <= qt; kt++){
    f32x4 sc4[4];
#pragma unroll
    for (int sub = 0; sub < 4; sub++){
      const short* kp = kp0 + (size_t)(kt * 64 + sub * 16 + lr) * DD;
      bf16x8 ka  = *(const bf16x8*)&kp[lg * 8];
      bf16x8 kb8 = *(const bf16x8*)&kp[32 + lg * 8];
      f32x4 t = {};
      t = __builtin_amdgcn_mfma_f32_16x16x32_bf16(qf0, ka,  t, 0, 0, 0);
      t = __builtin_amdgcn_mfma_f32_16x16x32_bf16(qf1, kb8, t, 0, 0, 0);
#pragma unroll
      for (int r = 0; r < 4; r++) t[r] *= 0.125f;
      sc4[sub] = t;
    }
    if (kt == qt){
#pragma unroll
      for (int sub = 0; sub < 4; sub++)
#pragma unroll
        for (int r = 0; r < 4; r++)
          if (16 * sub + lr > 16 * w + 4 * lg + r) sc4[sub][r] = -1e30f;
    }

    float pm[4];
#pragma unroll
    for (int r = 0; r < 4; r++)
      pm[r] = fmaxf(fmaxf(sc4[0][r], sc4[1][r]), fmaxf(sc4[2][r], sc4[3][r]));
#pragma unroll
    for (int off = 1; off < 16; off <<= 1)
#pragma unroll
      for (int r = 0; r < 4; r++) pm[r] = fmaxf(pm[r], __shfl_xor(pm[r], off));

    float scl[4], rs[4];
#pragma unroll
    for (int r = 0; r < 4; r++){
      float mn = fmaxf(m[r], pm[r]);
      scl[r] = __expf(m[r] - mn);
      m[r] = mn;
      rs[r] = 0.0f;
    }
#pragma unroll
    for (int sub = 0; sub < 4; sub++)
#pragma unroll
      for (int r = 0; r < 4; r++){
        float p = __expf(sc4[sub][r] - m[r]);
        sc4[sub][r] = p;
        rs[r] += p;
      }
#pragma unroll
    for (int off = 1; off < 16; off <<= 1)
#pragma unroll
      for (int r = 0; r < 4; r++) rs[r] += __shfl_xor(rs[r], off);
#pragma unroll
    for (int r = 0; r < 4; r++) l[r] = l[r] * scl[r] + rs[r];
#pragma unroll
    for (int nb = 0; nb < 4; nb++)
#pragma unroll
      for (int r = 0; r < 4; r++) acc[nb][r] *= scl[r];

    // P -> per-wave LDS (transpose to A-fragment layout)
#pragma unroll
    for (int sub = 0; sub < 4; sub++)
#pragma unroll
      for (int r = 0; r < 4; r++)
        pw[(4 * lg + r) * 72 + sub * 16 + lr] = f2bf(sc4[sub][r]);

    bf16x8 pf0 = *(const bf16x8*)&pw[lr * 72 + lg * 8];
    bf16x8 pf1 = *(const bf16x8*)&pw[lr * 72 + 32 + lg * 8];

#pragma unroll
    for (int nb = 0; nb < 4; nb++){
      const short* vp = vt0 + (size_t)(nb * 16 + lr) * SS + kt * 64;
      bf16x8 va  = *(const bf16x8*)&vp[lg * 8];
      bf16x8 vb8 = *(const bf16x8*)&vp[32 + lg * 8];
      acc[nb] = __builtin_amdgcn_mfma_f32_16x16x32_bf16(pf0, va,  acc[nb], 0, 0, 0);
      acc[nb] = __builtin_amdgcn_mfma_f32_16x16x32_bf16(pf1, vb8, acc[nb], 0, 0, 0);
    }
  }

#pragma unroll
  for (int r = 0; r < 4; r++){
    float inv = 1.0f / l[r];
    int row = qbase + 4 * lg + r;
#pragma unroll
    for (int nb = 0; nb < 4; nb++)
      ctxb[(size_t)(b * SS + row) * DD + h * HDIM + nb * 16 + lr] = f2bf(acc[nb][r] * inv);
  }
}

// ---------------- LayerNorm(a+b) ----------------
template<bool WBF16>
__global__ __launch_bounds__(256) void ln_kernel(const float* __restrict__ a,
                                                 const float* __restrict__ bsrc,
                                                 const float* __restrict__ g,
                                                 const float* __restrict__ be,
                                                 float* __restrict__ of,
                                                 short* __restrict__ ob){
  int row = blockIdx.x, tid = threadIdx.x;
  float4 av = *(const float4*)&a[(size_t)row * DD + tid * 4];
  float4 bv = *(const float4*)&bsrc[(size_t)row * DD + tid * 4];
  float x0 = av.x + bv.x, x1 = av.y + bv.y, x2 = av.z + bv.z, x3 = av.w + bv.w;
  float s = x0 + x1 + x2 + x3;
  float q = x0 * x0 + x1 * x1 + x2 * x2 + x3 * x3;
#pragma unroll
  for (int off = 32; off; off >>= 1){ s += __shfl_xor(s, off); q += __shfl_xor(q, off); }
  __shared__ float red[8];
  if ((tid & 63) == 0){ red[tid >> 6] = s; red[4 + (tid >> 6)] = q; }
  __syncthreads();
  s = red[0] + red[1] + red[2] + red[3];
  q = red[4] + red[5] + red[6] + red[7];
  float mean = s * (1.0f / DD);
  float var  = q * (1.0f / DD) - mean * mean;
  float rstd = rsqrtf(var + 1e-5f);
  float4 gv  = *(const float4*)&g[tid * 4];
  float4 bev = *(const float4*)&be[tid * 4];
  float y0 = (x0 - mean) * rstd * gv.x + bev.x;
  float y1 = (x1 - mean) * rstd * gv.y + bev.y;
  float y2 = (x2 - mean) * rstd * gv.z + bev.z;
  float y3 = (x3 - mean) * rstd * gv.w + bev.w;
  *(float4*)&of[(size_t)row * DD + tid * 4] = make_float4(y0, y1, y2, y3);
  if (WBF16){
    bf16x4 sb; sb[0]=f2bf(y0); sb[1]=f2bf(y1); sb[2]=f2bf(y2); sb[3]=f2bf(y3);
    *(bf16x4*)&ob[(size_t)row * DD + tid * 4] = sb;
  }
}

// ---------------- cross-entropy ----------------
__global__ __launch_bounds__(256) void loss_row_kernel(const float* __restrict__ logits,
                                                       const int* __restrict__ tgt,
                                                       float* __restrict__ outp){
  int row = blockIdx.x, tid = threadIdx.x;
  float4 v = *(const float4*)&logits[(size_t)row * DD + tid * 4];
  float mx = fmaxf(fmaxf(v.x, v.y), fmaxf(v.z, v.w));
#pragma unroll
  for (int off = 32; off; off >>= 1) mx = fmaxf(mx, __shfl_xor(mx, off));
  __shared__ float red[8];
  if ((tid & 63) == 0) red[tid >> 6] = mx;
  __syncthreads();
  mx = fmaxf(fmaxf(red[0], red[1]), fmaxf(red[2], red[3]));
  float se = expf(v.x - mx) + expf(v.y - mx) + expf(v.z - mx) + expf(v.w - mx);
#pragma unroll
  for (int off = 32; off; off >>= 1) se += __shfl_xor(se, off);
  __syncthreads();
  if ((tid & 63) == 0) red[4 + (tid >> 6)] = se;
  __syncthreads();
  if (tid == 0){
    float tot = red[4] + red[5] + red[6] + red[7];
    outp[row] = mx + logf(tot) - logits[(size_t)row * DD + tgt[row]];
  }
}

__global__ __launch_bounds__(256) void loss_reduce_kernel(const float* __restrict__ pr,
                                                          float* __restrict__ outp){
  int tid = threadIdx.x;
  float s = 0.0f;
  for (int i = tid; i < MM; i += 256) s += pr[i];
#pragma unroll
  for (int off = 32; off; off >>= 1) s += __shfl_xor(s, off);
  __shared__ float red[4];
  if ((tid & 63) == 0) red[tid >> 6] = s;
  __syncthreads();
  if (tid == 0) outp[0] = (red[0] + red[1] + red[2] + red[3]) * (1.0f / MM);
}

// ---------------- launch ----------------
extern "C" void kernel_launch(void* const* d_in, const int* in_sizes, int n_in,
                              void* d_out, int out_size, void* d_ws, size_t ws_size,
                              hipStream_t stream){
  const int*   inputs  = (const int*)  d_in[0];
  const int*   targets = (const int*)  d_in[1];
  const float* wte     = (const float*)d_in[2];
  const float* wq      = (const float*)d_in[3];
  const float* bq      = (const float*)d_in[4];
  const float* wk      = (const float*)d_in[5];
  const float* bk      = (const float*)d_in[6];
  const float* wv      = (const float*)d_in[7];
  const float* bvv     = (const float*)d_in[8];
  const float* wo      = (const float*)d_in[9];
  const float* bo      = (const float*)d_in[10];
  const float* w1      = (const float*)d_in[11];
  const float* b1      = (const float*)d_in[12];
  const float* w2      = (const float*)d_in[13];
  const float* b2      = (const float*)d_in[14];
  const float* ln1g    = (const float*)d_in[15];
  const float* ln1b    = (const float*)d_in[16];
  const float* ln2g    = (const float*)d_in[17];
  const float* ln2b    = (const float*)d_in[18];
  float* out = (float*)d_out;

  char* ws = (char*)d_ws;
  const size_t MB = 1024 * 1024;
  short* wqkvt = (short*)(ws + 0 * MB);    // 6MB: wq^T | wk^T | wv^T  [3072][1024]
  short* wqt   = (short*)(ws + 0 * MB);
  short* wkt   = (short*)(ws + 2 * MB);
  short* wvt   = (short*)(ws + 4 * MB);
  short* wot   = (short*)(ws + 6 * MB);    // 2MB
  short* w1t   = (short*)(ws + 8 * MB);    // 8MB
  short* w2t   = (short*)(ws + 16 * MB);   // 8MB
  float* xf    = (float*)(ws + 24 * MB);   // 16MB
  short* xb    = (short*)(ws + 40 * MB);   // 8MB (dead after QKV; lrow overlays)
  short* qbuf  = (short*)(ws + 48 * MB);   // 8MB
  short* kbuf  = (short*)(ws + 56 * MB);   // 8MB
  short* vtb   = (short*)(ws + 64 * MB);   // 8MB  V^T [B][H][64][S]
  short* ctxb  = (short*)(ws + 72 * MB);   // 8MB
  float* atto  = (float*)(ws + 80 * MB);   // 16MB
  float* adnf  = (float*)(ws + 96 * MB);   // 16MB
  short* adnb  = (short*)(ws + 112 * MB);  // 8MB
  short* h1b   = (short*)(ws + 48 * MB);   // 32MB, reuses q/k/vt/ctx (dead after proj)
  float* hf    = (float*)(ws + 120 * MB);  // 16MB
  float* bqkv  = (float*)(ws + 136 * MB);  // 12KB
  float* lrow  = (float*)(ws + 40 * MB);   // 16KB (overlays dead xb)

  dim3 tb(32, 8);
  trans_bf16_kernel<<<dim3(32, 32),  tb, 0, stream>>>(wq, wqt, DD, DD);
  trans_bf16_kernel<<<dim3(32, 32),  tb, 0, stream>>>(wk, wkt, DD, DD);
  trans_bf16_kernel<<<dim3(32, 32),  tb, 0, stream>>>(wv, wvt, DD, DD);
  trans_bf16_kernel<<<dim3(32, 32),  tb, 0, stream>>>(wo, wot, DD, DD);
  trans_bf16_kernel<<<dim3(128, 32), tb, 0, stream>>>(w1, w1t, DD, FF);
  trans_bf16_kernel<<<dim3(32, 128), tb, 0, stream>>>(w2, w2t, FF, DD);
  concat_bias_kernel<<<12, 256, 0, stream>>>(bq, bk, bvv, bqkv);

  embed_kernel<<<4096, 256, 0, stream>>>(inputs, wte, xf, xb);

  // fused QKV GEMM: [4096,1024] x [1024,3072] -> q,k row-major + v transposed
  gemm128_kernel<2, false><<<dim3(24, 32), 256, 0, stream>>>(
      xb, wqkvt, bqkv, nullptr, nullptr, qbuf, kbuf, vtb, MM, 3 * DD, DD);

  attn_kernel<<<dim3(16, 16, 4), 256, 0, stream>>>(qbuf, kbuf, vtb, ctxb);

  gemm64_kernel<<<dim3(16, 32), 256, 0, stream>>>(ctxb, wot, bo, atto, MM, DD, DD);

  ln_kernel<true><<<4096, 256, 0, stream>>>(xf, atto, ln1g, ln1b, adnf, adnb);

  gemm128_kernel<0, true><<<dim3(32, 32), 256, 0, stream>>>(
      adnb, w1t, b1, nullptr, h1b, nullptr, nullptr, nullptr, MM, FF, DD);

  gemm64_kernel<<<dim3(16, 32), 256, 0, stream>>>(h1b, w2t, b2, hf, MM, DD, FF);

  ln_kernel<false><<<4096, 256, 0, stream>>>(hf, adnf, ln2g, ln2b, out, nullptr);

  loss_row_kernel<<<4096, 256, 0, stream>>>(out, targets, lrow);
  loss_reduce_kernel<<<1, 256, 0, stream>>>(lrow, out + (size_t)MM * DD);
}

// Round 4
// 309.146 us; speedup vs baseline: 1.3959x; 1.3297x over previous
//
#include <hip/hip_runtime.h>
#include <math.h>

// Problem constants
#define BB 4
#define SS 1024
#define DD 1024
#define HH 16
#define HDIM 64
#define FF 4096
#define MM 4096   // B*S

typedef short bf16x8 __attribute__((ext_vector_type(8)));
typedef short bf16x4 __attribute__((ext_vector_type(4)));
typedef float f32x4  __attribute__((ext_vector_type(4)));

static __device__ __forceinline__ short f2bf(float f){
  unsigned u = __float_as_uint(f);
  u += 0x7FFFu + ((u >> 16) & 1u);   // RNE
  return (short)(u >> 16);
}

// async global->LDS, 16B per lane, LDS dest = base + lane*16 (wave-uniform base)
static __device__ __forceinline__ void gl_lds16(const short* g, short* l){
  __builtin_amdgcn_global_load_lds((const __attribute__((address_space(1))) unsigned int*)g,
                                   (__attribute__((address_space(3))) unsigned int*)l,
                                   16, 0, 0);
}

// ---------------- weight f32 -> bf16 transposed ----------------
__global__ __launch_bounds__(256) void trans_bf16_kernel(const float* __restrict__ src,
                                                         short* __restrict__ dst,
                                                         int R, int C){
  __shared__ float t[32][33];
  int c0 = blockIdx.x * 32, r0 = blockIdx.y * 32;
  int tx = threadIdx.x, ty = threadIdx.y;  // (32,8)
#pragma unroll
  for (int i = 0; i < 32; i += 8)
    t[ty + i][tx] = src[(size_t)(r0 + ty + i) * C + (c0 + tx)];
  __syncthreads();
#pragma unroll
  for (int i = 0; i < 32; i += 8)
    dst[(size_t)(c0 + ty + i) * R + (r0 + tx)] = f2bf(t[tx][ty + i]);
}

__global__ __launch_bounds__(256) void concat_bias_kernel(const float* __restrict__ a,
                                                          const float* __restrict__ b,
                                                          const float* __restrict__ c,
                                                          float* __restrict__ dst){
  int t = blockIdx.x * 256 + threadIdx.x;   // 3072
  float v = (t < 1024) ? a[t] : (t < 2048 ? b[t - 1024] : c[t - 2048]);
  dst[t] = v;
}

// ---------------- embedding + sinusoidal PE ----------------
__global__ __launch_bounds__(256) void embed_kernel(const int* __restrict__ inputs,
                                                    const float* __restrict__ wte,
                                                    float* __restrict__ xf,
                                                    short* __restrict__ xb){
  int idx4 = blockIdx.x * 256 + threadIdx.x;
  int row = idx4 >> 8;
  int d   = (idx4 & 255) * 4;
  int s   = row & (SS - 1);
  int tok = inputs[row];
  float4 w = *(const float4*)&wte[(size_t)tok * DD + d];
  const float cdiv = -9.210340371976184f / 512.0f;
  int i0 = d >> 1;
  float ang0 = (float)s * expf((float)i0 * cdiv);
  float ang1 = (float)s * expf((float)(i0 + 1) * cdiv);
  float x0 = w.x + sinf(ang0);
  float x1 = w.y + cosf(ang0);
  float x2 = w.z + sinf(ang1);
  float x3 = w.w + cosf(ang1);
  *(float4*)&xf[(size_t)row * DD + d] = make_float4(x0, x1, x2, x3);
  bf16x4 sb; sb[0]=f2bf(x0); sb[1]=f2bf(x1); sb[2]=f2bf(x2); sb[3]=f2bf(x3);
  *(bf16x4*)&xb[(size_t)row * DD + d] = sb;
}

// ---------------- 128x128 MFMA GEMM (m97 structure, global_load_lds) ----------------
// MODE 0: bf16 row-major (opt GELU); 1: f32 row-major; 2: QKV split (q,k row-major; v transposed)
template<int MODE, bool GELU>
__global__ __launch_bounds__(256) void gemm128_kernel(const short* __restrict__ A,
    const short* __restrict__ Bt, const float* __restrict__ bias,
    float* __restrict__ Cf, short* __restrict__ Cb,
    short* __restrict__ qo, short* __restrict__ ko, short* __restrict__ vto,
    int M, int N, int K){
  __shared__ __align__(16) short a_lds[128 * 32];
  __shared__ __align__(16) short b_lds[128 * 32];
  int tid = threadIdx.x;
  int m0 = blockIdx.y * 128, n0 = blockIdx.x * 128;
  int w = tid >> 6, lane = tid & 63, lr = lane & 15, lg = lane >> 4;
  int wm = (w & 1) * 64, wn = (w >> 1) * 64;
  int srow = lane >> 2, scol = (lane & 3) * 8;
  f32x4 acc[4][4] = {};

  for (int k0 = 0; k0 < K; k0 += 32){
#pragma unroll
    for (int i = 0; i < 2; i++){
      int rb = (w + 4 * i) * 16;
      gl_lds16(&A [(size_t)(m0 + rb + srow) * K + k0 + scol], &a_lds[rb * 32]);
      gl_lds16(&Bt[(size_t)(n0 + rb + srow) * K + k0 + scol], &b_lds[rb * 32]);
    }
    asm volatile("s_waitcnt vmcnt(0)" ::: "memory");
    __syncthreads();
    bf16x8 af[4], bfr[4];
#pragma unroll
    for (int mi = 0; mi < 4; mi++)
      af[mi] = *(const bf16x8*)&a_lds[(wm + mi * 16 + lr) * 32 + lg * 8];
#pragma unroll
    for (int ni = 0; ni < 4; ni++)
      bfr[ni] = *(const bf16x8*)&b_lds[(wn + ni * 16 + lr) * 32 + lg * 8];
#pragma unroll
    for (int mi = 0; mi < 4; mi++)
#pragma unroll
      for (int ni = 0; ni < 4; ni++)
        acc[mi][ni] = __builtin_amdgcn_mfma_f32_16x16x32_bf16(af[mi], bfr[ni], acc[mi][ni], 0, 0, 0);
    __syncthreads();
  }

#pragma unroll
  for (int mi = 0; mi < 4; mi++){
#pragma unroll
    for (int ni = 0; ni < 4; ni++){
      int ng = n0 + wn + ni * 16 + lr;
      float bv = bias[ng];
      int mg0 = m0 + wm + mi * 16 + 4 * lg;   // 4 consecutive rows
      if (MODE == 2){
        int sel = n0 >> 10;   // uniform per block (128 | 1024)
        if (sel == 2){
          int d = ng & 1023; int hh = d >> 6, nn = d & 63;
          int bI = mg0 >> 10, sI = mg0 & 1023;
          bf16x4 pk;
#pragma unroll
          for (int r = 0; r < 4; r++) pk[r] = f2bf(acc[mi][ni][r] + bv);
          *(bf16x4*)&vto[(((size_t)(bI * HH + hh)) * HDIM + nn) * SS + sI] = pk;
        } else {
          short* dst = (sel == 0) ? qo : ko;
#pragma unroll
          for (int r = 0; r < 4; r++)
            dst[(size_t)(mg0 + r) * DD + (ng & 1023)] = f2bf(acc[mi][ni][r] + bv);
        }
      } else {
#pragma unroll
        for (int r = 0; r < 4; r++){
          float v = acc[mi][ni][r] + bv;
          if (GELU) v = 0.5f * v * (1.0f + erff(v * 0.70710678118654752f));
          if (MODE == 0) Cb[(size_t)(mg0 + r) * N + ng] = f2bf(v);
          else           Cf[(size_t)(mg0 + r) * N + ng] = v;
        }
      }
    }
  }
}

// ---------------- 128x64 MFMA GEMM (2 blocks/CU for N=1024 shapes), f32 out ----------------
__global__ __launch_bounds__(256) void gemm64_kernel(const short* __restrict__ A,
    const short* __restrict__ Bt, const float* __restrict__ bias,
    float* __restrict__ Cf, int M, int N, int K){
  __shared__ __align__(16) short a_lds[128 * 32];
  __shared__ __align__(16) short b_lds[64 * 32];
  int tid = threadIdx.x;
  int m0 = blockIdx.y * 128, n0 = blockIdx.x * 64;
  int w = tid >> 6, lane = tid & 63, lr = lane & 15, lg = lane >> 4;
  int wm = w * 32;
  int srow = lane >> 2, scol = (lane & 3) * 8;
  f32x4 acc[2][4] = {};

  for (int k0 = 0; k0 < K; k0 += 32){
#pragma unroll
    for (int i = 0; i < 2; i++){
      int rb = (w + 4 * i) * 16;
      gl_lds16(&A[(size_t)(m0 + rb + srow) * K + k0 + scol], &a_lds[rb * 32]);
    }
    { int rb = w * 16;
      gl_lds16(&Bt[(size_t)(n0 + rb + srow) * K + k0 + scol], &b_lds[rb * 32]); }
    asm volatile("s_waitcnt vmcnt(0)" ::: "memory");
    __syncthreads();
    bf16x8 af[2], bfr[4];
#pragma unroll
    for (int mi = 0; mi < 2; mi++)
      af[mi] = *(const bf16x8*)&a_lds[(wm + mi * 16 + lr) * 32 + lg * 8];
#pragma unroll
    for (int ni = 0; ni < 4; ni++)
      bfr[ni] = *(const bf16x8*)&b_lds[(ni * 16 + lr) * 32 + lg * 8];
#pragma unroll
    for (int mi = 0; mi < 2; mi++)
#pragma unroll
      for (int ni = 0; ni < 4; ni++)
        acc[mi][ni] = __builtin_amdgcn_mfma_f32_16x16x32_bf16(af[mi], bfr[ni], acc[mi][ni], 0, 0, 0);
    __syncthreads();
  }

#pragma unroll
  for (int mi = 0; mi < 2; mi++)
#pragma unroll
    for (int ni = 0; ni < 4; ni++){
      int ng = n0 + ni * 16 + lr;
      float bv = bias[ng];
      int mg0 = m0 + wm + mi * 16 + 4 * lg;
#pragma unroll
      for (int r = 0; r < 4; r++)
        Cf[(size_t)(mg0 + r) * N + ng] = acc[mi][ni][r] + bv;
    }
}

// ---------------- causal flash attention v3 ----------------
// Block = (qpair, h, b): q-tiles Tlo=qp, Thi=15-qp (64 rows each; wave w owns 16 rows of each).
// K/V^T tiles cooperatively staged in LDS (double-buffered, global_load_lds w=16,
// T2 XOR swizzle via pre-swizzled global source). Balanced: every block = 17 tile-computes.
__global__ __launch_bounds__(256) void attn_kernel(const short* __restrict__ qb,
                                                   const short* __restrict__ kb,
                                                   const short* __restrict__ vtb,
                                                   short* __restrict__ ctxb){
  __shared__ __align__(16) short k_lds[2][64 * 64];   // 16KB
  __shared__ __align__(16) short v_lds[2][64 * 64];   // 16KB
  __shared__ __align__(16) short p_lds[4][2][16 * 72]; // 18KB
  int qp = blockIdx.x, h = blockIdx.y, b = blockIdx.z;
  int Tlo = qp, Thi = 15 - qp;
  int tid = threadIdx.x, w = tid >> 6, lane = tid & 63, lr = lane & 15, lg = lane >> 4;

  const short* kp0 = kb  + (size_t)b * SS * DD + h * HDIM;
  const short* vt0 = vtb + (size_t)(b * HH + h) * HDIM * SS;   // [64][1024]

  // Q fragments for both tiles
  bf16x8 qf0[2], qf1[2];
#pragma unroll
  for (int ti = 0; ti < 2; ti++){
    int T = ti ? Thi : Tlo;
    const short* qp_ = qb + ((size_t)(b * SS + T * 64 + w * 16 + lr) * DD + h * HDIM);
    qf0[ti] = *(const bf16x8*)&qp_[lg * 8];
    qf1[ti] = *(const bf16x8*)&qp_[32 + lg * 8];
  }

  float m[2][4], l[2][4];
  f32x4 acc[2][4] = {};
#pragma unroll
  for (int ti = 0; ti < 2; ti++)
#pragma unroll
    for (int r = 0; r < 4; r++){ m[ti][r] = -1e30f; l[ti][r] = 0.0f; }

  // staging: K tile [64 tok][64 d], V^T tile [64 d][64 tok]; chunk ^= (row&7) source swizzle
  int srow8 = lane >> 3;                       // 0..7
  int sjs   = (lane & 7) ^ srow8;              // swizzled 16B chunk
  auto STAGE = [&](int buf, int kt){
#pragma unroll
    for (int i = 0; i < 2; i++){
      int rb  = (w + 4 * i) * 8;               // 8-row block (wave-uniform)
      int row = rb + srow8;
      gl_lds16(kp0 + (size_t)(kt * 64 + row) * DD + sjs * 8, &k_lds[buf][rb * 64]);
      gl_lds16(vt0 + (size_t)row * SS + kt * 64 + sjs * 8,   &v_lds[buf][rb * 64]);
    }
  };

  int cur = 0;
  STAGE(0, 0);
  asm volatile("s_waitcnt vmcnt(0)" ::: "memory");
  __syncthreads();

  bf16x8 pf0[2], pf1[2];
  for (int kt = 0; kt <= Thi; kt++){
    if (kt < Thi) STAGE(cur ^ 1, kt + 1);

    // K fragments from LDS (shared by both q-tiles), swizzled read
    bf16x8 kf0[4], kf1[4];
#pragma unroll
    for (int sub = 0; sub < 4; sub++){
      int r = sub * 16 + lr;
      kf0[sub] = *(const bf16x8*)&k_lds[cur][r * 64 + ((lg     ^ (r & 7)) * 8)];
      kf1[sub] = *(const bf16x8*)&k_lds[cur][r * 64 + (((lg+4) ^ (r & 7)) * 8)];
    }

#pragma unroll
    for (int ti = 0; ti < 2; ti++){
      int T = ti ? Thi : Tlo;
      if (kt > T) continue;
      f32x4 sc4[4];
#pragma unroll
      for (int sub = 0; sub < 4; sub++){
        f32x4 t = {};
        t = __builtin_amdgcn_mfma_f32_16x16x32_bf16(qf0[ti], kf0[sub], t, 0, 0, 0);
        t = __builtin_amdgcn_mfma_f32_16x16x32_bf16(qf1[ti], kf1[sub], t, 0, 0, 0);
#pragma unroll
        for (int r = 0; r < 4; r++) t[r] *= 0.125f;
        sc4[sub] = t;
      }
      if (kt == T){
#pragma unroll
        for (int sub = 0; sub < 4; sub++)
#pragma unroll
          for (int r = 0; r < 4; r++)
            if (16 * sub + lr > 16 * w + 4 * lg + r) sc4[sub][r] = -1e30f;
      }

      float pm[4];
#pragma unroll
      for (int r = 0; r < 4; r++)
        pm[r] = fmaxf(fmaxf(sc4[0][r], sc4[1][r]), fmaxf(sc4[2][r], sc4[3][r]));
#pragma unroll
      for (int off = 1; off < 16; off <<= 1)
#pragma unroll
        for (int r = 0; r < 4; r++) pm[r] = fmaxf(pm[r], __shfl_xor(pm[r], off));

      float scl[4], rs[4];
#pragma unroll
      for (int r = 0; r < 4; r++){
        float mn = fmaxf(m[ti][r], pm[r]);
        scl[r] = __expf(m[ti][r] - mn);
        m[ti][r] = mn;
        rs[r] = 0.0f;
      }
#pragma unroll
      for (int sub = 0; sub < 4; sub++)
#pragma unroll
        for (int r = 0; r < 4; r++){
          float p = __expf(sc4[sub][r] - m[ti][r]);
          sc4[sub][r] = p;
          rs[r] += p;
        }
#pragma unroll
      for (int off = 1; off < 16; off <<= 1)
#pragma unroll
        for (int r = 0; r < 4; r++) rs[r] += __shfl_xor(rs[r], off);
#pragma unroll
      for (int r = 0; r < 4; r++) l[ti][r] = l[ti][r] * scl[r] + rs[r];
#pragma unroll
      for (int nb = 0; nb < 4; nb++)
#pragma unroll
        for (int r = 0; r < 4; r++) acc[ti][nb][r] *= scl[r];

      // P -> per-wave LDS (transpose to A-fragment layout)
      short* pw = &p_lds[w][ti][0];
#pragma unroll
      for (int sub = 0; sub < 4; sub++)
#pragma unroll
        for (int r = 0; r < 4; r++)
          pw[(4 * lg + r) * 72 + sub * 16 + lr] = f2bf(sc4[sub][r]);
      pf0[ti] = *(const bf16x8*)&pw[lr * 72 + lg * 8];
      pf1[ti] = *(const bf16x8*)&pw[lr * 72 + 32 + lg * 8];
    }

    // V fragments from LDS (shared), swizzled read
    bf16x8 vf0[4], vf1[4];
#pragma unroll
    for (int nb = 0; nb < 4; nb++){
      int r = nb * 16 + lr;
      vf0[nb] = *(const bf16x8*)&v_lds[cur][r * 64 + ((lg     ^ (r & 7)) * 8)];
      vf1[nb] = *(const bf16x8*)&v_lds[cur][r * 64 + (((lg+4) ^ (r & 7)) * 8)];
    }

#pragma unroll
    for (int ti = 0; ti < 2; ti++){
      int T = ti ? Thi : Tlo;
      if (kt > T) continue;
#pragma unroll
      for (int nb = 0; nb < 4; nb++){
        acc[ti][nb] = __builtin_amdgcn_mfma_f32_16x16x32_bf16(pf0[ti], vf0[nb], acc[ti][nb], 0, 0, 0);
        acc[ti][nb] = __builtin_amdgcn_mfma_f32_16x16x32_bf16(pf1[ti], vf1[nb], acc[ti][nb], 0, 0, 0);
      }
    }

    asm volatile("s_waitcnt vmcnt(0)" ::: "memory");
    __syncthreads();
    cur ^= 1;
  }

#pragma unroll
  for (int ti = 0; ti < 2; ti++){
    int T = ti ? Thi : Tlo;
#pragma unroll
    for (int r = 0; r < 4; r++){
      float inv = 1.0f / l[ti][r];
      int row = T * 64 + w * 16 + 4 * lg + r;
#pragma unroll
      for (int nb = 0; nb < 4; nb++)
        ctxb[(size_t)(b * SS + row) * DD + h * HDIM + nb * 16 + lr] = f2bf(acc[ti][nb][r] * inv);
    }
  }
}

// ---------------- LayerNorm(a+b) ----------------
template<bool WBF16>
__global__ __launch_bounds__(256) void ln_kernel(const float* __restrict__ a,
                                                 const float* __restrict__ bsrc,
                                                 const float* __restrict__ g,
                                                 const float* __restrict__ be,
                                                 float* __restrict__ of,
                                                 short* __restrict__ ob){
  int row = blockIdx.x, tid = threadIdx.x;
  float4 av = *(const float4*)&a[(size_t)row * DD + tid * 4];
  float4 bv = *(const float4*)&bsrc[(size_t)row * DD + tid * 4];
  float x0 = av.x + bv.x, x1 = av.y + bv.y, x2 = av.z + bv.z, x3 = av.w + bv.w;
  float s = x0 + x1 + x2 + x3;
  float q = x0 * x0 + x1 * x1 + x2 * x2 + x3 * x3;
#pragma unroll
  for (int off = 32; off; off >>= 1){ s += __shfl_xor(s, off); q += __shfl_xor(q, off); }
  __shared__ float red[8];
  if ((tid & 63) == 0){ red[tid >> 6] = s; red[4 + (tid >> 6)] = q; }
  __syncthreads();
  s = red[0] + red[1] + red[2] + red[3];
  q = red[4] + red[5] + red[6] + red[7];
  float mean = s * (1.0f / DD);
  float var  = q * (1.0f / DD) - mean * mean;
  float rstd = rsqrtf(var + 1e-5f);
  float4 gv  = *(const float4*)&g[tid * 4];
  float4 bev = *(const float4*)&be[tid * 4];
  float y0 = (x0 - mean) * rstd * gv.x + bev.x;
  float y1 = (x1 - mean) * rstd * gv.y + bev.y;
  float y2 = (x2 - mean) * rstd * gv.z + bev.z;
  float y3 = (x3 - mean) * rstd * gv.w + bev.w;
  *(float4*)&of[(size_t)row * DD + tid * 4] = make_float4(y0, y1, y2, y3);
  if (WBF16){
    bf16x4 sb; sb[0]=f2bf(y0); sb[1]=f2bf(y1); sb[2]=f2bf(y2); sb[3]=f2bf(y3);
    *(bf16x4*)&ob[(size_t)row * DD + tid * 4] = sb;
  }
}

// ---------------- cross-entropy ----------------
__global__ __launch_bounds__(256) void loss_row_kernel(const float* __restrict__ logits,
                                                       const int* __restrict__ tgt,
                                                       float* __restrict__ outp){
  int row = blockIdx.x, tid = threadIdx.x;
  float4 v = *(const float4*)&logits[(size_t)row * DD + tid * 4];
  float mx = fmaxf(fmaxf(v.x, v.y), fmaxf(v.z, v.w));
#pragma unroll
  for (int off = 32; off; off >>= 1) mx = fmaxf(mx, __shfl_xor(mx, off));
  __shared__ float red[8];
  if ((tid & 63) == 0) red[tid >> 6] = mx;
  __syncthreads();
  mx = fmaxf(fmaxf(red[0], red[1]), fmaxf(red[2], red[3]));
  float se = expf(v.x - mx) + expf(v.y - mx) + expf(v.z - mx) + expf(v.w - mx);
#pragma unroll
  for (int off = 32; off; off >>= 1) se += __shfl_xor(se, off);
  __syncthreads();
  if ((tid & 63) == 0) red[4 + (tid >> 6)] = se;
  __syncthreads();
  if (tid == 0){
    float tot = red[4] + red[5] + red[6] + red[7];
    outp[row] = mx + logf(tot) - logits[(size_t)row * DD + tgt[row]];
  }
}

__global__ __launch_bounds__(256) void loss_reduce_kernel(const float* __restrict__ pr,
                                                          float* __restrict__ outp){
  int tid = threadIdx.x;
  float s = 0.0f;
  for (int i = tid; i < MM; i += 256) s += pr[i];
#pragma unroll
  for (int off = 32; off; off >>= 1) s += __shfl_xor(s, off);
  __shared__ float red[4];
  if ((tid & 63) == 0) red[tid >> 6] = s;
  __syncthreads();
  if (tid == 0) outp[0] = (red[0] + red[1] + red[2] + red[3]) * (1.0f / MM);
}

// ---------------- launch ----------------
extern "C" void kernel_launch(void* const* d_in, const int* in_sizes, int n_in,
                              void* d_out, int out_size, void* d_ws, size_t ws_size,
                              hipStream_t stream){
  const int*   inputs  = (const int*)  d_in[0];
  const int*   targets = (const int*)  d_in[1];
  const float* wte     = (const float*)d_in[2];
  const float* wq      = (const float*)d_in[3];
  const float* bq      = (const float*)d_in[4];
  const float* wk      = (const float*)d_in[5];
  const float* bk      = (const float*)d_in[6];
  const float* wv      = (const float*)d_in[7];
  const float* bvv     = (const float*)d_in[8];
  const float* wo      = (const float*)d_in[9];
  const float* bo      = (const float*)d_in[10];
  const float* w1      = (const float*)d_in[11];
  const float* b1      = (const float*)d_in[12];
  const float* w2      = (const float*)d_in[13];
  const float* b2      = (const float*)d_in[14];
  const float* ln1g    = (const float*)d_in[15];
  const float* ln1b    = (const float*)d_in[16];
  const float* ln2g    = (const float*)d_in[17];
  const float* ln2b    = (const float*)d_in[18];
  float* out = (float*)d_out;

  char* ws = (char*)d_ws;
  const size_t MB = 1024 * 1024;
  short* wqkvt = (short*)(ws + 0 * MB);    // 6MB: wq^T | wk^T | wv^T  [3072][1024]
  short* wqt   = (short*)(ws + 0 * MB);
  short* wkt   = (short*)(ws + 2 * MB);
  short* wvt   = (short*)(ws + 4 * MB);
  short* wot   = (short*)(ws + 6 * MB);    // 2MB
  short* w1t   = (short*)(ws + 8 * MB);    // 8MB
  short* w2t   = (short*)(ws + 16 * MB);   // 8MB
  float* xf    = (float*)(ws + 24 * MB);   // 16MB
  short* xb    = (short*)(ws + 40 * MB);   // 8MB (dead after QKV; lrow overlays)
  short* qbuf  = (short*)(ws + 48 * MB);   // 8MB
  short* kbuf  = (short*)(ws + 56 * MB);   // 8MB
  short* vtb   = (short*)(ws + 64 * MB);   // 8MB  V^T [B][H][64][S]
  short* ctxb  = (short*)(ws + 72 * MB);   // 8MB
  float* atto  = (float*)(ws + 80 * MB);   // 16MB
  float* adnf  = (float*)(ws + 96 * MB);   // 16MB
  short* adnb  = (short*)(ws + 112 * MB);  // 8MB
  short* h1b   = (short*)(ws + 48 * MB);   // 32MB, reuses q/k/vt/ctx (dead after proj)
  float* hf    = (float*)(ws + 120 * MB);  // 16MB
  float* bqkv  = (float*)(ws + 136 * MB);  // 12KB
  float* lrow  = (float*)(ws + 40 * MB);   // 16KB (overlays dead xb)

  dim3 tb(32, 8);
  trans_bf16_kernel<<<dim3(32, 32),  tb, 0, stream>>>(wq, wqt, DD, DD);
  trans_bf16_kernel<<<dim3(32, 32),  tb, 0, stream>>>(wk, wkt, DD, DD);
  trans_bf16_kernel<<<dim3(32, 32),  tb, 0, stream>>>(wv, wvt, DD, DD);
  trans_bf16_kernel<<<dim3(32, 32),  tb, 0, stream>>>(wo, wot, DD, DD);
  trans_bf16_kernel<<<dim3(128, 32), tb, 0, stream>>>(w1, w1t, DD, FF);
  trans_bf16_kernel<<<dim3(32, 128), tb, 0, stream>>>(w2, w2t, FF, DD);
  concat_bias_kernel<<<12, 256, 0, stream>>>(bq, bk, bvv, bqkv);

  embed_kernel<<<4096, 256, 0, stream>>>(inputs, wte, xf, xb);

  // fused QKV GEMM: [4096,1024] x [1024,3072] -> q,k row-major + v transposed
  gemm128_kernel<2, false><<<dim3(24, 32), 256, 0, stream>>>(
      xb, wqkvt, bqkv, nullptr, nullptr, qbuf, kbuf, vtb, MM, 3 * DD, DD);

  attn_kernel<<<dim3(8, 16, 4), 256, 0, stream>>>(qbuf, kbuf, vtb, ctxb);

  gemm64_kernel<<<dim3(16, 32), 256, 0, stream>>>(ctxb, wot, bo, atto, MM, DD, DD);

  ln_kernel<true><<<4096, 256, 0, stream>>>(xf, atto, ln1g, ln1b, adnf, adnb);

  gemm128_kernel<0, true><<<dim3(32, 32), 256, 0, stream>>>(
      adnb, w1t, b1, nullptr, h1b, nullptr, nullptr, nullptr, MM, FF, DD);

  gemm64_kernel<<<dim3(16, 32), 256, 0, stream>>>(h1b, w2t, b2, hf, MM, DD, FF);

  ln_kernel<false><<<4096, 256, 0, stream>>>(hf, adnf, ln2g, ln2b, out, nullptr);

  loss_row_kernel<<<4096, 256, 0, stream>>>(out, targets, lrow);
  loss_reduce_kernel<<<1, 256, 0, stream>>>(lrow, out + (size_t)MM * DD);
}

// Round 5
// 308.961 us; speedup vs baseline: 1.3967x; 1.0006x over previous
//
#include <hip/hip_runtime.h>
#include <math.h>

// Problem constants
#define BB 4
#define SS 1024
#define DD 1024
#define HH 16
#define HDIM 64
#define FF 4096
#define MM 4096   // B*S

typedef short bf16x8 __attribute__((ext_vector_type(8)));
typedef short bf16x4 __attribute__((ext_vector_type(4)));
typedef float f32x4  __attribute__((ext_vector_type(4)));

static __device__ __forceinline__ short f2bf(float f){
  unsigned u = __float_as_uint(f);
  u += 0x7FFFu + ((u >> 16) & 1u);   // RNE
  return (short)(u >> 16);
}

// async global->LDS, 16B per lane, LDS dest = base + lane*16 (wave-uniform base)
static __device__ __forceinline__ void gl_lds16(const short* g, short* l){
  __builtin_amdgcn_global_load_lds((const __attribute__((address_space(1))) unsigned int*)g,
                                   (__attribute__((address_space(3))) unsigned int*)l,
                                   16, 0, 0);
}

// ---------------- weight f32 -> bf16 transposed ----------------
__global__ __launch_bounds__(256) void trans_bf16_kernel(const float* __restrict__ src,
                                                         short* __restrict__ dst,
                                                         int R, int C){
  __shared__ float t[32][33];
  int c0 = blockIdx.x * 32, r0 = blockIdx.y * 32;
  int tx = threadIdx.x, ty = threadIdx.y;  // (32,8)
#pragma unroll
  for (int i = 0; i < 32; i += 8)
    t[ty + i][tx] = src[(size_t)(r0 + ty + i) * C + (c0 + tx)];
  __syncthreads();
#pragma unroll
  for (int i = 0; i < 32; i += 8)
    dst[(size_t)(c0 + ty + i) * R + (r0 + tx)] = f2bf(t[tx][ty + i]);
}

__global__ __launch_bounds__(256) void concat_bias_kernel(const float* __restrict__ a,
                                                          const float* __restrict__ b,
                                                          const float* __restrict__ c,
                                                          float* __restrict__ dst){
  int t = blockIdx.x * 256 + threadIdx.x;   // 3072
  float v = (t < 1024) ? a[t] : (t < 2048 ? b[t - 1024] : c[t - 2048]);
  dst[t] = v;
}

// ---------------- embedding + sinusoidal PE ----------------
__global__ __launch_bounds__(256) void embed_kernel(const int* __restrict__ inputs,
                                                    const float* __restrict__ wte,
                                                    float* __restrict__ xf,
                                                    short* __restrict__ xb){
  int idx4 = blockIdx.x * 256 + threadIdx.x;
  int row = idx4 >> 8;
  int d   = (idx4 & 255) * 4;
  int s   = row & (SS - 1);
  int tok = inputs[row];
  float4 w = *(const float4*)&wte[(size_t)tok * DD + d];
  const float cdiv = -9.210340371976184f / 512.0f;
  int i0 = d >> 1;
  float ang0 = (float)s * expf((float)i0 * cdiv);
  float ang1 = (float)s * expf((float)(i0 + 1) * cdiv);
  float x0 = w.x + sinf(ang0);
  float x1 = w.y + cosf(ang0);
  float x2 = w.z + sinf(ang1);
  float x3 = w.w + cosf(ang1);
  *(float4*)&xf[(size_t)row * DD + d] = make_float4(x0, x1, x2, x3);
  bf16x4 sb; sb[0]=f2bf(x0); sb[1]=f2bf(x1); sb[2]=f2bf(x2); sb[3]=f2bf(x3);
  *(bf16x4*)&xb[(size_t)row * DD + d] = sb;
}

// ---------------- 128x128 MFMA GEMM, 2-phase double-buffered ----------------
// MODE 0: bf16 row-major (opt GELU); 1: f32 row-major; 2: QKV split (q,k row-major; v transposed)
template<int MODE, bool GELU>
__global__ __launch_bounds__(256) void gemm128_kernel(const short* __restrict__ A,
    const short* __restrict__ Bt, const float* __restrict__ bias,
    float* __restrict__ Cf, short* __restrict__ Cb,
    short* __restrict__ qo, short* __restrict__ ko, short* __restrict__ vto,
    int M, int N, int K){
  __shared__ __align__(16) short a_lds[2][128 * 32];
  __shared__ __align__(16) short b_lds[2][128 * 32];
  int tid = threadIdx.x;
  // bijective XCD swizzle (nwg % 8 == 0 for all our grids)
  int lid = blockIdx.y * gridDim.x + blockIdx.x;
  int cpx = (gridDim.x * gridDim.y) >> 3;
  int swz = (lid & 7) * cpx + (lid >> 3);
  int n0 = (swz % gridDim.x) * 128;
  int m0 = (swz / gridDim.x) * 128;
  int w = tid >> 6, lane = tid & 63, lr = lane & 15, lg = lane >> 4;
  int wm = (w & 1) * 64, wn = (w >> 1) * 64;
  int srow = lane >> 2, scol = (lane & 3) * 8;
  f32x4 acc[4][4] = {};

  const short* Arow = A  + (size_t)(m0 + srow) * K + scol;
  const short* Brow = Bt + (size_t)(n0 + srow) * K + scol;

  auto STAGE = [&](int buf, int k0){
#pragma unroll
    for (int i = 0; i < 2; i++){
      int rb = (w + 4 * i) * 16;
      gl_lds16(Arow + (size_t)rb * K + k0, &a_lds[buf][rb * 32]);
      gl_lds16(Brow + (size_t)rb * K + k0, &b_lds[buf][rb * 32]);
    }
  };

  STAGE(0, 0);
  __syncthreads();     // drains vmcnt -> buf0 ready
  int cur = 0;
  for (int k0 = 0; k0 < K; k0 += 32){
    int nxt = k0 + 32;
    if (nxt < K) STAGE(cur ^ 1, nxt);   // prefetch overlaps compute below
    bf16x8 af[4], bfr[4];
#pragma unroll
    for (int mi = 0; mi < 4; mi++)
      af[mi] = *(const bf16x8*)&a_lds[cur][(wm + mi * 16 + lr) * 32 + lg * 8];
#pragma unroll
    for (int ni = 0; ni < 4; ni++)
      bfr[ni] = *(const bf16x8*)&b_lds[cur][(wn + ni * 16 + lr) * 32 + lg * 8];
#pragma unroll
    for (int mi = 0; mi < 4; mi++)
#pragma unroll
      for (int ni = 0; ni < 4; ni++)
        acc[mi][ni] = __builtin_amdgcn_mfma_f32_16x16x32_bf16(af[mi], bfr[ni], acc[mi][ni], 0, 0, 0);
    __syncthreads();   // drains vmcnt(0): prefetch landed; all reads of cur done
    cur ^= 1;
  }

#pragma unroll
  for (int mi = 0; mi < 4; mi++){
#pragma unroll
    for (int ni = 0; ni < 4; ni++){
      int ng = n0 + wn + ni * 16 + lr;
      float bv = bias[ng];
      int mg0 = m0 + wm + mi * 16 + 4 * lg;   // 4 consecutive rows
      if (MODE == 2){
        int sel = n0 >> 10;   // uniform per block (128 | 1024)
        if (sel == 2){
          int d = ng & 1023; int hh = d >> 6, nn = d & 63;
          int bI = mg0 >> 10, sI = mg0 & 1023;
          bf16x4 pk;
#pragma unroll
          for (int r = 0; r < 4; r++) pk[r] = f2bf(acc[mi][ni][r] + bv);
          *(bf16x4*)&vto[(((size_t)(bI * HH + hh)) * HDIM + nn) * SS + sI] = pk;
        } else {
          short* dst = (sel == 0) ? qo : ko;
#pragma unroll
          for (int r = 0; r < 4; r++)
            dst[(size_t)(mg0 + r) * DD + (ng & 1023)] = f2bf(acc[mi][ni][r] + bv);
        }
      } else {
#pragma unroll
        for (int r = 0; r < 4; r++){
          float v = acc[mi][ni][r] + bv;
          if (GELU) v = 0.5f * v * (1.0f + erff(v * 0.70710678118654752f));
          if (MODE == 0) Cb[(size_t)(mg0 + r) * N + ng] = f2bf(v);
          else           Cf[(size_t)(mg0 + r) * N + ng] = v;
        }
      }
    }
  }
}

// ---------------- causal flash attention v3 ----------------
// Block = (qpair, h, b): q-tiles Tlo=qp, Thi=15-qp (64 rows each; wave w owns 16 rows of each).
// K/V^T tiles cooperatively staged in LDS (double-buffered, global_load_lds w=16,
// T2 XOR swizzle via pre-swizzled global source). Balanced: every block = 17 tile-computes.
__global__ __launch_bounds__(256) void attn_kernel(const short* __restrict__ qb,
                                                   const short* __restrict__ kb,
                                                   const short* __restrict__ vtb,
                                                   short* __restrict__ ctxb){
  __shared__ __align__(16) short k_lds[2][64 * 64];   // 16KB
  __shared__ __align__(16) short v_lds[2][64 * 64];   // 16KB
  __shared__ __align__(16) short p_lds[4][2][16 * 72]; // 18KB
  int qp = blockIdx.x, h = blockIdx.y, b = blockIdx.z;
  int Tlo = qp, Thi = 15 - qp;
  int tid = threadIdx.x, w = tid >> 6, lane = tid & 63, lr = lane & 15, lg = lane >> 4;

  const short* kp0 = kb  + (size_t)b * SS * DD + h * HDIM;
  const short* vt0 = vtb + (size_t)(b * HH + h) * HDIM * SS;   // [64][1024]

  // Q fragments for both tiles
  bf16x8 qf0[2], qf1[2];
#pragma unroll
  for (int ti = 0; ti < 2; ti++){
    int T = ti ? Thi : Tlo;
    const short* qp_ = qb + ((size_t)(b * SS + T * 64 + w * 16 + lr) * DD + h * HDIM);
    qf0[ti] = *(const bf16x8*)&qp_[lg * 8];
    qf1[ti] = *(const bf16x8*)&qp_[32 + lg * 8];
  }

  float m[2][4], l[2][4];
  f32x4 acc[2][4] = {};
#pragma unroll
  for (int ti = 0; ti < 2; ti++)
#pragma unroll
    for (int r = 0; r < 4; r++){ m[ti][r] = -1e30f; l[ti][r] = 0.0f; }

  // staging: K tile [64 tok][64 d], V^T tile [64 d][64 tok]; chunk ^= (row&7) source swizzle
  int srow8 = lane >> 3;                       // 0..7
  int sjs   = (lane & 7) ^ srow8;              // swizzled 16B chunk
  auto STAGE = [&](int buf, int kt){
#pragma unroll
    for (int i = 0; i < 2; i++){
      int rb  = (w + 4 * i) * 8;               // 8-row block (wave-uniform)
      int row = rb + srow8;
      gl_lds16(kp0 + (size_t)(kt * 64 + row) * DD + sjs * 8, &k_lds[buf][rb * 64]);
      gl_lds16(vt0 + (size_t)row * SS + kt * 64 + sjs * 8,   &v_lds[buf][rb * 64]);
    }
  };

  int cur = 0;
  STAGE(0, 0);
  asm volatile("s_waitcnt vmcnt(0)" ::: "memory");
  __syncthreads();

  bf16x8 pf0[2], pf1[2];
  for (int kt = 0; kt <= Thi; kt++){
    if (kt < Thi) STAGE(cur ^ 1, kt + 1);

    // K fragments from LDS (shared by both q-tiles), swizzled read
    bf16x8 kf0[4], kf1[4];
#pragma unroll
    for (int sub = 0; sub < 4; sub++){
      int r = sub * 16 + lr;
      kf0[sub] = *(const bf16x8*)&k_lds[cur][r * 64 + ((lg     ^ (r & 7)) * 8)];
      kf1[sub] = *(const bf16x8*)&k_lds[cur][r * 64 + (((lg+4) ^ (r & 7)) * 8)];
    }

#pragma unroll
    for (int ti = 0; ti < 2; ti++){
      int T = ti ? Thi : Tlo;
      if (kt > T) continue;
      f32x4 sc4[4];
#pragma unroll
      for (int sub = 0; sub < 4; sub++){
        f32x4 t = {};
        t = __builtin_amdgcn_mfma_f32_16x16x32_bf16(qf0[ti], kf0[sub], t, 0, 0, 0);
        t = __builtin_amdgcn_mfma_f32_16x16x32_bf16(qf1[ti], kf1[sub], t, 0, 0, 0);
#pragma unroll
        for (int r = 0; r < 4; r++) t[r] *= 0.125f;
        sc4[sub] = t;
      }
      if (kt == T){
#pragma unroll
        for (int sub = 0; sub < 4; sub++)
#pragma unroll
          for (int r = 0; r < 4; r++)
            if (16 * sub + lr > 16 * w + 4 * lg + r) sc4[sub][r] = -1e30f;
      }

      float pm[4];
#pragma unroll
      for (int r = 0; r < 4; r++)
        pm[r] = fmaxf(fmaxf(sc4[0][r], sc4[1][r]), fmaxf(sc4[2][r], sc4[3][r]));
#pragma unroll
      for (int off = 1; off < 16; off <<= 1)
#pragma unroll
        for (int r = 0; r < 4; r++) pm[r] = fmaxf(pm[r], __shfl_xor(pm[r], off));

      float scl[4], rs[4];
#pragma unroll
      for (int r = 0; r < 4; r++){
        float mn = fmaxf(m[ti][r], pm[r]);
        scl[r] = __expf(m[ti][r] - mn);
        m[ti][r] = mn;
        rs[r] = 0.0f;
      }
#pragma unroll
      for (int sub = 0; sub < 4; sub++)
#pragma unroll
        for (int r = 0; r < 4; r++){
          float p = __expf(sc4[sub][r] - m[ti][r]);
          sc4[sub][r] = p;
          rs[r] += p;
        }
#pragma unroll
      for (int off = 1; off < 16; off <<= 1)
#pragma unroll
        for (int r = 0; r < 4; r++) rs[r] += __shfl_xor(rs[r], off);
#pragma unroll
      for (int r = 0; r < 4; r++) l[ti][r] = l[ti][r] * scl[r] + rs[r];
#pragma unroll
      for (int nb = 0; nb < 4; nb++)
#pragma unroll
        for (int r = 0; r < 4; r++) acc[ti][nb][r] *= scl[r];

      // P -> per-wave LDS (transpose to A-fragment layout)
      short* pw = &p_lds[w][ti][0];
#pragma unroll
      for (int sub = 0; sub < 4; sub++)
#pragma unroll
        for (int r = 0; r < 4; r++)
          pw[(4 * lg + r) * 72 + sub * 16 + lr] = f2bf(sc4[sub][r]);
      pf0[ti] = *(const bf16x8*)&pw[lr * 72 + lg * 8];
      pf1[ti] = *(const bf16x8*)&pw[lr * 72 + 32 + lg * 8];
    }

    // V fragments from LDS (shared), swizzled read
    bf16x8 vf0[4], vf1[4];
#pragma unroll
    for (int nb = 0; nb < 4; nb++){
      int r = nb * 16 + lr;
      vf0[nb] = *(const bf16x8*)&v_lds[cur][r * 64 + ((lg     ^ (r & 7)) * 8)];
      vf1[nb] = *(const bf16x8*)&v_lds[cur][r * 64 + (((lg+4) ^ (r & 7)) * 8)];
    }

#pragma unroll
    for (int ti = 0; ti < 2; ti++){
      int T = ti ? Thi : Tlo;
      if (kt > T) continue;
#pragma unroll
      for (int nb = 0; nb < 4; nb++){
        acc[ti][nb] = __builtin_amdgcn_mfma_f32_16x16x32_bf16(pf0[ti], vf0[nb], acc[ti][nb], 0, 0, 0);
        acc[ti][nb] = __builtin_amdgcn_mfma_f32_16x16x32_bf16(pf1[ti], vf1[nb], acc[ti][nb], 0, 0, 0);
      }
    }

    asm volatile("s_waitcnt vmcnt(0)" ::: "memory");
    __syncthreads();
    cur ^= 1;
  }

#pragma unroll
  for (int ti = 0; ti < 2; ti++){
    int T = ti ? Thi : Tlo;
#pragma unroll
    for (int r = 0; r < 4; r++){
      float inv = 1.0f / l[ti][r];
      int row = T * 64 + w * 16 + 4 * lg + r;
#pragma unroll
      for (int nb = 0; nb < 4; nb++)
        ctxb[(size_t)(b * SS + row) * DD + h * HDIM + nb * 16 + lr] = f2bf(acc[ti][nb][r] * inv);
    }
  }
}

// ---------------- LayerNorm(a+b) ----------------
template<bool WBF16>
__global__ __launch_bounds__(256) void ln_kernel(const float* __restrict__ a,
                                                 const float* __restrict__ bsrc,
                                                 const float* __restrict__ g,
                                                 const float* __restrict__ be,
                                                 float* __restrict__ of,
                                                 short* __restrict__ ob){
  int row = blockIdx.x, tid = threadIdx.x;
  float4 av = *(const float4*)&a[(size_t)row * DD + tid * 4];
  float4 bv = *(const float4*)&bsrc[(size_t)row * DD + tid * 4];
  float x0 = av.x + bv.x, x1 = av.y + bv.y, x2 = av.z + bv.z, x3 = av.w + bv.w;
  float s = x0 + x1 + x2 + x3;
  float q = x0 * x0 + x1 * x1 + x2 * x2 + x3 * x3;
#pragma unroll
  for (int off = 32; off; off >>= 1){ s += __shfl_xor(s, off); q += __shfl_xor(q, off); }
  __shared__ float red[8];
  if ((tid & 63) == 0){ red[tid >> 6] = s; red[4 + (tid >> 6)] = q; }
  __syncthreads();
  s = red[0] + red[1] + red[2] + red[3];
  q = red[4] + red[5] + red[6] + red[7];
  float mean = s * (1.0f / DD);
  float var  = q * (1.0f / DD) - mean * mean;
  float rstd = rsqrtf(var + 1e-5f);
  float4 gv  = *(const float4*)&g[tid * 4];
  float4 bev = *(const float4*)&be[tid * 4];
  float y0 = (x0 - mean) * rstd * gv.x + bev.x;
  float y1 = (x1 - mean) * rstd * gv.y + bev.y;
  float y2 = (x2 - mean) * rstd * gv.z + bev.z;
  float y3 = (x3 - mean) * rstd * gv.w + bev.w;
  *(float4*)&of[(size_t)row * DD + tid * 4] = make_float4(y0, y1, y2, y3);
  if (WBF16){
    bf16x4 sb; sb[0]=f2bf(y0); sb[1]=f2bf(y1); sb[2]=f2bf(y2); sb[3]=f2bf(y3);
    *(bf16x4*)&ob[(size_t)row * DD + tid * 4] = sb;
  }
}

// ---------------- cross-entropy ----------------
__global__ __launch_bounds__(256) void loss_row_kernel(const float* __restrict__ logits,
                                                       const int* __restrict__ tgt,
                                                       float* __restrict__ outp){
  int row = blockIdx.x, tid = threadIdx.x;
  float4 v = *(const float4*)&logits[(size_t)row * DD + tid * 4];
  float mx = fmaxf(fmaxf(v.x, v.y), fmaxf(v.z, v.w));
#pragma unroll
  for (int off = 32; off; off >>= 1) mx = fmaxf(mx, __shfl_xor(mx, off));
  __shared__ float red[8];
  if ((tid & 63) == 0) red[tid >> 6] = mx;
  __syncthreads();
  mx = fmaxf(fmaxf(red[0], red[1]), fmaxf(red[2], red[3]));
  float se = expf(v.x - mx) + expf(v.y - mx) + expf(v.z - mx) + expf(v.w - mx);
#pragma unroll
  for (int off = 32; off; off >>= 1) se += __shfl_xor(se, off);
  __syncthreads();
  if ((tid & 63) == 0) red[4 + (tid >> 6)] = se;
  __syncthreads();
  if (tid == 0){
    float tot = red[4] + red[5] + red[6] + red[7];
    outp[row] = mx + logf(tot) - logits[(size_t)row * DD + tgt[row]];
  }
}

__global__ __launch_bounds__(256) void loss_reduce_kernel(const float* __restrict__ pr,
                                                          float* __restrict__ outp){
  int tid = threadIdx.x;
  float s = 0.0f;
  for (int i = tid; i < MM; i += 256) s += pr[i];
#pragma unroll
  for (int off = 32; off; off >>= 1) s += __shfl_xor(s, off);
  __shared__ float red[4];
  if ((tid & 63) == 0) red[tid >> 6] = s;
  __syncthreads();
  if (tid == 0) outp[0] = (red[0] + red[1] + red[2] + red[3]) * (1.0f / MM);
}

// ---------------- launch ----------------
extern "C" void kernel_launch(void* const* d_in, const int* in_sizes, int n_in,
                              void* d_out, int out_size, void* d_ws, size_t ws_size,
                              hipStream_t stream){
  const int*   inputs  = (const int*)  d_in[0];
  const int*   targets = (const int*)  d_in[1];
  const float* wte     = (const float*)d_in[2];
  const float* wq      = (const float*)d_in[3];
  const float* bq      = (const float*)d_in[4];
  const float* wk      = (const float*)d_in[5];
  const float* bk      = (const float*)d_in[6];
  const float* wv      = (const float*)d_in[7];
  const float* bvv     = (const float*)d_in[8];
  const float* wo      = (const float*)d_in[9];
  const float* bo      = (const float*)d_in[10];
  const float* w1      = (const float*)d_in[11];
  const float* b1      = (const float*)d_in[12];
  const float* w2      = (const float*)d_in[13];
  const float* b2      = (const float*)d_in[14];
  const float* ln1g    = (const float*)d_in[15];
  const float* ln1b    = (const float*)d_in[16];
  const float* ln2g    = (const float*)d_in[17];
  const float* ln2b    = (const float*)d_in[18];
  float* out = (float*)d_out;

  char* ws = (char*)d_ws;
  const size_t MB = 1024 * 1024;
  short* wqkvt = (short*)(ws + 0 * MB);    // 6MB: wq^T | wk^T | wv^T  [3072][1024]
  short* wqt   = (short*)(ws + 0 * MB);
  short* wkt   = (short*)(ws + 2 * MB);
  short* wvt   = (short*)(ws + 4 * MB);
  short* wot   = (short*)(ws + 6 * MB);    // 2MB
  short* w1t   = (short*)(ws + 8 * MB);    // 8MB
  short* w2t   = (short*)(ws + 16 * MB);   // 8MB
  float* xf    = (float*)(ws + 24 * MB);   // 16MB
  short* xb    = (short*)(ws + 40 * MB);   // 8MB (dead after QKV; lrow overlays)
  short* qbuf  = (short*)(ws + 48 * MB);   // 8MB
  short* kbuf  = (short*)(ws + 56 * MB);   // 8MB
  short* vtb   = (short*)(ws + 64 * MB);   // 8MB  V^T [B][H][64][S]
  short* ctxb  = (short*)(ws + 72 * MB);   // 8MB
  float* atto  = (float*)(ws + 80 * MB);   // 16MB
  float* adnf  = (float*)(ws + 96 * MB);   // 16MB
  short* adnb  = (short*)(ws + 112 * MB);  // 8MB
  short* h1b   = (short*)(ws + 48 * MB);   // 32MB, reuses q/k/vt/ctx (dead after proj)
  float* hf    = (float*)(ws + 120 * MB);  // 16MB
  float* bqkv  = (float*)(ws + 136 * MB);  // 12KB
  float* lrow  = (float*)(ws + 40 * MB);   // 16KB (overlays dead xb)

  dim3 tb(32, 8);
  trans_bf16_kernel<<<dim3(32, 32),  tb, 0, stream>>>(wq, wqt, DD, DD);
  trans_bf16_kernel<<<dim3(32, 32),  tb, 0, stream>>>(wk, wkt, DD, DD);
  trans_bf16_kernel<<<dim3(32, 32),  tb, 0, stream>>>(wv, wvt, DD, DD);
  trans_bf16_kernel<<<dim3(32, 32),  tb, 0, stream>>>(wo, wot, DD, DD);
  trans_bf16_kernel<<<dim3(128, 32), tb, 0, stream>>>(w1, w1t, DD, FF);
  trans_bf16_kernel<<<dim3(32, 128), tb, 0, stream>>>(w2, w2t, FF, DD);
  concat_bias_kernel<<<12, 256, 0, stream>>>(bq, bk, bvv, bqkv);

  embed_kernel<<<4096, 256, 0, stream>>>(inputs, wte, xf, xb);

  // fused QKV GEMM: [4096,1024] x [1024,3072] -> q,k row-major + v transposed
  gemm128_kernel<2, false><<<dim3(24, 32), 256, 0, stream>>>(
      xb, wqkvt, bqkv, nullptr, nullptr, qbuf, kbuf, vtb, MM, 3 * DD, DD);

  attn_kernel<<<dim3(8, 16, 4), 256, 0, stream>>>(qbuf, kbuf, vtb, ctxb);

  // attention out-proj: [4096,1024] x [1024,1024] -> f32
  gemm128_kernel<1, false><<<dim3(8, 32), 256, 0, stream>>>(
      ctxb, wot, bo, atto, nullptr, nullptr, nullptr, nullptr, MM, DD, DD);

  ln_kernel<true><<<4096, 256, 0, stream>>>(xf, atto, ln1g, ln1b, adnf, adnb);

  gemm128_kernel<0, true><<<dim3(32, 32), 256, 0, stream>>>(
      adnb, w1t, b1, nullptr, h1b, nullptr, nullptr, nullptr, MM, FF, DD);

  // FFN2: [4096,4096] x [4096,1024] -> f32
  gemm128_kernel<1, false><<<dim3(8, 32), 256, 0, stream>>>(
      h1b, w2t, b2, hf, nullptr, nullptr, nullptr, nullptr, MM, DD, FF);

  ln_kernel<false><<<4096, 256, 0, stream>>>(hf, adnf, ln2g, ln2b, out, nullptr);

  loss_row_kernel<<<4096, 256, 0, stream>>>(out, targets, lrow);
  loss_reduce_kernel<<<1, 256, 0, stream>>>(lrow, out + (size_t)MM * DD);
}